// Round 2
// baseline (128.143 us; speedup 1.0000x reference)
//
#include <hip/hip_runtime.h>
#include <stdint.h>

#define TB 2048
#define DM 256

typedef __attribute__((ext_vector_type(4))) float f32x4;
typedef __attribute__((ext_vector_type(8))) short short8;

__device__ __forceinline__ unsigned short f2bf(float f) {
  union { float f; unsigned u; } v; v.f = f;
  unsigned r = v.u + 0x7fffu + ((v.u >> 16) & 1u);
  return (unsigned short)(r >> 16);
}
__device__ __forceinline__ unsigned pack2(float a, float b) {
  return (unsigned)f2bf(a) | ((unsigned)f2bf(b) << 16);
}

// ---------------- kernel 1: decay table ----------------
// td[d] = alpha * eta / (1 + d^|beta|) * (1/sqrt(32))   (prior scale + 1/sqrt(dk) folded)
__global__ void k_tables(const float* __restrict__ eta, const float* __restrict__ beta,
                         const float* __restrict__ alpha, float* __restrict__ td) {
  int i = blockIdx.x * 256 + threadIdx.x;
  if (i < TB) {
    float ab = fabsf(beta[0]);
    float dt = powf((float)i, ab);
    td[i] = alpha[0] * eta[0] / (1.0f + dt) * 0.17677669529663687f;
  }
}

// ---------------- kernel 2: QKV projection ----------------
// out = x @ W^T + b.  Q,K stored bf16 [B*T][256]; V stored transposed bf16 [B][256][T].
__global__ __launch_bounds__(256, 2) void k_proj(
    const float* __restrict__ x,
    const float* __restrict__ Wq, const float* __restrict__ bq,
    const float* __restrict__ Wk, const float* __restrict__ bk,
    const float* __restrict__ Wv, const float* __restrict__ bv,
    unsigned short* __restrict__ Qb, unsigned short* __restrict__ Kb,
    unsigned short* __restrict__ Vtb) {
  __shared__ unsigned short Al[64 * 256];  // 32KB, swizzled: chunk ^= row&7
  __shared__ unsigned short Bl[64 * 256];  // 32KB
  const int m0 = blockIdx.x * 64, n0 = blockIdx.y * 64, z = blockIdx.z;
  const int tid = threadIdx.x;
  const float* W = (z == 0) ? Wq : (z == 1) ? Wk : Wv;
  const float* bias = (z == 0) ? bq : (z == 1) ? bk : bv;

#pragma unroll
  for (int it = 0; it < 8; ++it) {
    int C = it * 256 + tid;            // 16B-chunk id, 0..2047 (32 chunks/row)
    int row = C >> 5, lc = C & 31;
    const float4* ga = (const float4*)(x + (size_t)(m0 + row) * 256 + lc * 8);
    float4 a0 = ga[0], a1 = ga[1];
    uint4 pa;
    pa.x = pack2(a0.x, a0.y); pa.y = pack2(a0.z, a0.w);
    pa.z = pack2(a1.x, a1.y); pa.w = pack2(a1.z, a1.w);
    *(uint4*)&Al[row * 256 + ((lc ^ (row & 7)) * 8)] = pa;
    const float4* gb = (const float4*)(W + (size_t)(n0 + row) * 256 + lc * 8);
    float4 b0 = gb[0], b1 = gb[1];
    uint4 pb;
    pb.x = pack2(b0.x, b0.y); pb.y = pack2(b0.z, b0.w);
    pb.z = pack2(b1.x, b1.y); pb.w = pack2(b1.z, b1.w);
    *(uint4*)&Bl[row * 256 + ((lc ^ (row & 7)) * 8)] = pb;
  }
  __syncthreads();

  const int w = tid >> 6, l = tid & 63, g = l >> 4, ql = l & 15;
  const int wm = w >> 1, wn = w & 1;
  f32x4 acc[2][2] = {};
#pragma unroll
  for (int kk = 0; kk < 8; ++kk) {
    short8 af[2], bf_[2];
#pragma unroll
    for (int mi = 0; mi < 2; ++mi) {
      int row = wm * 32 + mi * 16 + ql;
      af[mi] = *(const short8*)&Al[row * 256 + (((kk * 4 + g) ^ (row & 7)) * 8)];
    }
#pragma unroll
    for (int ni = 0; ni < 2; ++ni) {
      int row = wn * 32 + ni * 16 + ql;
      bf_[ni] = *(const short8*)&Bl[row * 256 + (((kk * 4 + g) ^ (row & 7)) * 8)];
    }
#pragma unroll
    for (int mi = 0; mi < 2; ++mi)
#pragma unroll
      for (int ni = 0; ni < 2; ++ni)
        acc[mi][ni] = __builtin_amdgcn_mfma_f32_16x16x32_bf16(af[mi], bf_[ni], acc[mi][ni], 0, 0, 0);
  }

#pragma unroll
  for (int ni = 0; ni < 2; ++ni) {
    int n = n0 + wn * 32 + ni * 16 + ql;
    float bs = bias[n];
#pragma unroll
    for (int mi = 0; mi < 2; ++mi) {
      int mb = m0 + wm * 32 + mi * 16 + 4 * g;  // D row = 4*(l>>4)+reg
      f32x4 v = acc[mi][ni];
      v.x += bs; v.y += bs; v.z += bs; v.w += bs;
      if (z == 2) {
        int batch = mb >> 11, t = mb & 2047;
        uint2 pv; pv.x = pack2(v.x, v.y); pv.y = pack2(v.z, v.w);
        *(uint2*)&Vtb[(size_t)(batch * 256 + n) * 2048 + t] = pv;
      } else {
        unsigned short* dst = (z == 0) ? Qb : Kb;
        dst[(size_t)(mb + 0) * 256 + n] = f2bf(v.x);
        dst[(size_t)(mb + 1) * 256 + n] = f2bf(v.y);
        dst[(size_t)(mb + 2) * 256 + n] = f2bf(v.z);
        dst[(size_t)(mb + 3) * 256 + n] = f2bf(v.w);
      }
    }
  }
}

// ---------------- kernel 3: fused causal attention with prior ----------------
// grid (64 q-tiles, 4 batches), 512 threads = 8 waves = 8 heads. QB=32, KB=64.
__global__ __launch_bounds__(512, 2) void k_attn(
    const unsigned short* __restrict__ Qb, const unsigned short* __restrict__ Kb,
    const unsigned short* __restrict__ Vtb, const float* __restrict__ oc,
    const float* __restrict__ td, unsigned short* __restrict__ Ab) {
  __shared__ unsigned short Kl[64 * 256];   // 32KB  K tile [k][h*32+d], chunk^=(row&7)
  __shared__ unsigned short Vl[256 * 64];   // 32KB  V^T tile [h*32+d][k], chunk^=(row&7)
  __shared__ unsigned short Pl[8][32 * 64]; // 32KB  per-wave P [q][k], chunk^=(q&7)
  __shared__ float Pr[32 * 64];             // 8KB   prior [q][k] f32, f32x4-chunk^=(q&15)
  const int qt = blockIdx.x, bb = blockIdx.y;
  const int q0 = qt * 32;
  const int tid = threadIdx.x;
  const int w = tid >> 6, l = tid & 63, g = l >> 4, ql = l & 15;
  const int h = w;

  // Q fragments (bf16, held for whole block)
  short8 qf[2];
#pragma unroll
  for (int qb = 0; qb < 2; ++qb)
    qf[qb] = *(const short8*)&Qb[(size_t)(bb * TB + q0 + qb * 16 + ql) * 256 + h * 32 + 8 * g];

  // this thread's prior-row oc (q side)
  const int pq = tid & 31, pck = tid >> 5;  // pck in [0,16)
  const float oq0 = oc[(size_t)(bb * TB + q0 + pq) * 3 + 0];
  const float oq1 = oc[(size_t)(bb * TB + q0 + pq) * 3 + 1];
  const float oq2 = oc[(size_t)(bb * TB + q0 + pq) * 3 + 2];

  f32x4 oacc[2][2] = {};                 // [db][qb], D rows = d, cols = q
  float mrow[2] = { -__builtin_inff(), -__builtin_inff() };
  float srow[2] = { 0.f, 0.f };
  const f32x4 zero4 = { 0.f, 0.f, 0.f, 0.f };

  const int nsteps = (qt + 2) >> 1;
  for (int st = 0; st < nsteps; ++st) {
    const int k0 = st * 64;
    // ---- stage K, V^T, prior ----
#pragma unroll
    for (int it = 0; it < 4; ++it) {
      int C = it * 512 + tid;
      {
        int row = C >> 5, lc = C & 31;  // K: 32 chunks/row
        uint4 v = *(const uint4*)&Kb[(size_t)(bb * TB + k0 + row) * 256 + lc * 8];
        *(uint4*)&Kl[row * 256 + ((lc ^ (row & 7)) * 8)] = v;
      }
      {
        int row = C >> 3, lc = C & 7;   // V^T: 8 chunks/row
        uint4 v = *(const uint4*)&Vtb[(size_t)(bb * 256 + row) * 2048 + k0 + lc * 8];
        *(uint4*)&Vl[row * 64 + ((lc ^ (row & 7)) * 8)] = v;
      }
    }
    {
      float pv[4];
#pragma unroll
      for (int j = 0; j < 4; ++j) {
        int kg = k0 + pck * 4 + j;
        float d0 = oq0 - oc[(size_t)(bb * TB + kg) * 3 + 0];
        float d1 = oq1 - oc[(size_t)(bb * TB + kg) * 3 + 1];
        float d2 = oq2 - oc[(size_t)(bb * TB + kg) * 3 + 2];
        float dist = d0 * d0 + d1 * d1 + d2 * d2;
        int dd = (q0 + pq) - kg; dd = dd < 0 ? -dd : dd;
        pv[j] = td[dd] * __expf(-dist);
      }
      f32x4 pvv = { pv[0], pv[1], pv[2], pv[3] };
      *(f32x4*)&Pr[pq * 64 + ((pck ^ (pq & 15)) * 4)] = pvv;
    }
    __syncthreads();

    // ---- S^T = mfma(K, Q): lane owns q = qb*16+ql, k = 16*kb+4*g+reg ----
    short8 kf[4];
#pragma unroll
    for (int kb = 0; kb < 4; ++kb) {
      int row = kb * 16 + ql;
      kf[kb] = *(const short8*)&Kl[row * 256 + (((h * 4 + g) ^ (row & 7)) * 8)];
    }
    const bool diag = (k0 + 64 > q0);
#pragma unroll
    for (int qb = 0; qb < 2; ++qb) {
      const int qq = qb * 16 + ql;
      const int qg = q0 + qq;
      f32x4 s[4];
#pragma unroll
      for (int kb = 0; kb < 4; ++kb)
        s[kb] = __builtin_amdgcn_mfma_f32_16x16x32_bf16(kf[kb], qf[qb], zero4, 0, 0, 0);
      float mt_ = -__builtin_inff();
#pragma unroll
      for (int kb = 0; kb < 4; ++kb) {
        f32x4 pr = *(const f32x4*)&Pr[qq * 64 + (((kb * 4 + g) ^ ql) * 4)];
        s[kb].x *= pr.x; s[kb].y *= pr.y; s[kb].z *= pr.z; s[kb].w *= pr.w;
        if (diag) {
          int kbase = k0 + kb * 16 + 4 * g;
          if (kbase + 0 > qg) s[kb].x = -__builtin_inff();
          if (kbase + 1 > qg) s[kb].y = -__builtin_inff();
          if (kbase + 2 > qg) s[kb].z = -__builtin_inff();
          if (kbase + 3 > qg) s[kb].w = -__builtin_inff();
        }
        mt_ = fmaxf(mt_, fmaxf(fmaxf(s[kb].x, s[kb].y), fmaxf(s[kb].z, s[kb].w)));
      }
      mt_ = fmaxf(mt_, __shfl_xor(mt_, 16));
      mt_ = fmaxf(mt_, __shfl_xor(mt_, 32));
      float mn = fmaxf(mrow[qb], mt_);
      float scale = __expf(mrow[qb] - mn);
      mrow[qb] = mn;
      float ssum = 0.f;
#pragma unroll
      for (int kb = 0; kb < 4; ++kb) {
        f32x4 p;
        p.x = __expf(s[kb].x - mn); p.y = __expf(s[kb].y - mn);
        p.z = __expf(s[kb].z - mn); p.w = __expf(s[kb].w - mn);
        ssum += (p.x + p.y) + (p.z + p.w);
        uint2 pp; pp.x = pack2(p.x, p.y); pp.y = pack2(p.z, p.w);
        int c16 = 2 * kb + (g >> 1);
        *(uint2*)&Pl[w][qq * 64 + ((c16 ^ (qq & 7)) * 8) + (g & 1) * 4] = pp;
      }
      srow[qb] = srow[qb] * scale + ssum;
#pragma unroll
      for (int db = 0; db < 2; ++db) {
        oacc[db][qb].x *= scale; oacc[db][qb].y *= scale;
        oacc[db][qb].z *= scale; oacc[db][qb].w *= scale;
      }
    }
    // make this wave's P LDS writes visible to its own cross-lane reads
    asm volatile("s_waitcnt lgkmcnt(0)" ::: "memory");

    // ---- PV: O^T[d][q] += sum_k V^T[d][k] * P[q][k] ----
#pragma unroll
    for (int ks = 0; ks < 2; ++ks) {
      short8 vf[2], pf[2];
#pragma unroll
      for (int db = 0; db < 2; ++db) {
        int row = h * 32 + db * 16 + ql;
        vf[db] = *(const short8*)&Vl[row * 64 + (((ks * 4 + g) ^ (row & 7)) * 8)];
      }
#pragma unroll
      for (int qb = 0; qb < 2; ++qb) {
        int qq = qb * 16 + ql;
        pf[qb] = *(const short8*)&Pl[w][qq * 64 + (((ks * 4 + g) ^ (qq & 7)) * 8)];
      }
#pragma unroll
      for (int db = 0; db < 2; ++db)
#pragma unroll
        for (int qb = 0; qb < 2; ++qb)
          oacc[db][qb] = __builtin_amdgcn_mfma_f32_16x16x32_bf16(vf[db], pf[qb], oacc[db][qb], 0, 0, 0);
    }
    __syncthreads();
  }

  // ---- epilogue: normalize rows, store attn-out bf16 ----
#pragma unroll
  for (int qb = 0; qb < 2; ++qb) {
    float s_ = srow[qb];
    s_ += __shfl_xor(s_, 16);
    s_ += __shfl_xor(s_, 32);
    float rinv = 1.0f / s_;
    int qq = qb * 16 + ql;
#pragma unroll
    for (int db = 0; db < 2; ++db) {
      f32x4 v = oacc[db][qb];
      uint2 pv;
      pv.x = pack2(v.x * rinv, v.y * rinv);
      pv.y = pack2(v.z * rinv, v.w * rinv);
      *(uint2*)&Ab[(size_t)(bb * TB + q0 + qq) * 256 + h * 32 + db * 16 + 4 * g] = pv;
    }
  }
}

// ---------------- kernel 4: output projection ----------------
__global__ __launch_bounds__(256, 2) void k_oproj(
    const unsigned short* __restrict__ Ab, const float* __restrict__ Wo,
    const float* __restrict__ bo, float* __restrict__ out) {
  __shared__ unsigned short Al[64 * 256];
  __shared__ unsigned short Bl[64 * 256];
  const int m0 = blockIdx.x * 64, n0 = blockIdx.y * 64;
  const int tid = threadIdx.x;
#pragma unroll
  for (int it = 0; it < 8; ++it) {
    int C = it * 256 + tid;
    int row = C >> 5, lc = C & 31;
    uint4 va = *(const uint4*)&Ab[(size_t)(m0 + row) * 256 + lc * 8];
    *(uint4*)&Al[row * 256 + ((lc ^ (row & 7)) * 8)] = va;
    const float4* gb = (const float4*)(Wo + (size_t)(n0 + row) * 256 + lc * 8);
    float4 b0 = gb[0], b1 = gb[1];
    uint4 pb;
    pb.x = pack2(b0.x, b0.y); pb.y = pack2(b0.z, b0.w);
    pb.z = pack2(b1.x, b1.y); pb.w = pack2(b1.z, b1.w);
    *(uint4*)&Bl[row * 256 + ((lc ^ (row & 7)) * 8)] = pb;
  }
  __syncthreads();

  const int w = tid >> 6, l = tid & 63, g = l >> 4, ql = l & 15;
  const int wm = w >> 1, wn = w & 1;
  f32x4 acc[2][2] = {};
#pragma unroll
  for (int kk = 0; kk < 8; ++kk) {
    short8 af[2], bf_[2];
#pragma unroll
    for (int mi = 0; mi < 2; ++mi) {
      int row = wm * 32 + mi * 16 + ql;
      af[mi] = *(const short8*)&Al[row * 256 + (((kk * 4 + g) ^ (row & 7)) * 8)];
    }
#pragma unroll
    for (int ni = 0; ni < 2; ++ni) {
      int row = wn * 32 + ni * 16 + ql;
      bf_[ni] = *(const short8*)&Bl[row * 256 + (((kk * 4 + g) ^ (row & 7)) * 8)];
    }
#pragma unroll
    for (int mi = 0; mi < 2; ++mi)
#pragma unroll
      for (int ni = 0; ni < 2; ++ni)
        acc[mi][ni] = __builtin_amdgcn_mfma_f32_16x16x32_bf16(af[mi], bf_[ni], acc[mi][ni], 0, 0, 0);
  }
#pragma unroll
  for (int ni = 0; ni < 2; ++ni) {
    int n = n0 + wn * 32 + ni * 16 + ql;
    float bs = bo[n];
#pragma unroll
    for (int mi = 0; mi < 2; ++mi) {
      int mb = m0 + wm * 32 + mi * 16 + 4 * g;
      out[(size_t)(mb + 0) * 256 + n] = acc[mi][ni].x + bs;
      out[(size_t)(mb + 1) * 256 + n] = acc[mi][ni].y + bs;
      out[(size_t)(mb + 2) * 256 + n] = acc[mi][ni].z + bs;
      out[(size_t)(mb + 3) * 256 + n] = acc[mi][ni].w + bs;
    }
  }
}

extern "C" void kernel_launch(void* const* d_in, const int* in_sizes, int n_in,
                              void* d_out, int out_size, void* d_ws, size_t ws_size,
                              hipStream_t stream) {
  const float* x    = (const float*)d_in[0];
  const float* oc   = (const float*)d_in[1];
  const float* Wq   = (const float*)d_in[2];
  const float* bq   = (const float*)d_in[3];
  const float* Wk   = (const float*)d_in[4];
  const float* bk   = (const float*)d_in[5];
  const float* Wv   = (const float*)d_in[6];
  const float* bv   = (const float*)d_in[7];
  const float* Wo   = (const float*)d_in[8];
  const float* bo   = (const float*)d_in[9];
  const float* eta  = (const float*)d_in[10];
  const float* beta = (const float*)d_in[11];
  const float* alpha= (const float*)d_in[12];

  unsigned short* Qb  = (unsigned short*)d_ws;
  unsigned short* Kb  = Qb + (size_t)8192 * 256;
  unsigned short* Vtb = Kb + (size_t)8192 * 256;
  unsigned short* Ab  = Vtb + (size_t)8192 * 256;
  float* td = (float*)(Ab + (size_t)8192 * 256);
  float* out = (float*)d_out;

  k_tables<<<dim3(8), dim3(256), 0, stream>>>(eta, beta, alpha, td);
  k_proj<<<dim3(128, 4, 3), dim3(256), 0, stream>>>(x, Wq, bq, Wk, bk, Wv, bv, Qb, Kb, Vtb);
  k_attn<<<dim3(64, 4), dim3(512), 0, stream>>>(Qb, Kb, Vtb, oc, td, Ab);
  k_oproj<<<dim3(128, 4), dim3(256), 0, stream>>>(Ab, Wo, bo, out);
}